// Round 2
// baseline (278.381 us; speedup 1.0000x reference)
//
#include <hip/hip_runtime.h>
#include <hip/hip_bf16.h>
#include <stdint.h>

#define SQ 8192
#define SK 8192
#define DH 128
#define BK 64
#define L2E 1.4426950408889634f

typedef __attribute__((ext_vector_type(8))) short bf16x8;
typedef __attribute__((ext_vector_type(4))) float f32x4;
typedef __attribute__((ext_vector_type(4))) short s16x4;

__device__ __forceinline__ short f2bf(float f) {
  uint32_t u = __builtin_bit_cast(uint32_t, f);
  u = (u + 0x7FFFu + ((u >> 16) & 1u)) >> 16;
  return (short)u;
}
__device__ __forceinline__ float bf2f(short s) {
  uint32_t u = ((uint32_t)(uint16_t)s) << 16;
  return __builtin_bit_cast(float, u);
}

// ---- prep 1: K fp32 -> bf16 hi + lo residual, layout [SK][DH] each ----
__global__ __launch_bounds__(256) void cvt_k_kernel(const float* __restrict__ K,
                                                    short* __restrict__ Khi,
                                                    short* __restrict__ Klo) {
  int idx = blockIdx.x * 256 + threadIdx.x;   // one float4 per thread
  float4 v = ((const float4*)K)[idx];
  s16x4 h, l;
  h.x = f2bf(v.x); l.x = f2bf(v.x - bf2f(h.x));
  h.y = f2bf(v.y); l.y = f2bf(v.y - bf2f(h.y));
  h.z = f2bf(v.z); l.z = f2bf(v.z - bf2f(h.z));
  h.w = f2bf(v.w); l.w = f2bf(v.w - bf2f(h.w));
  ((s16x4*)Khi)[idx] = h;
  ((s16x4*)Klo)[idx] = l;
}

// ---- prep 2: V fp32 [SK][DH] -> Vt bf16 [DH][SK] (transpose) ----
__global__ __launch_bounds__(256) void tr_v_kernel(const float* __restrict__ V,
                                                   short* __restrict__ Vt) {
  __shared__ short T[64][132];
  const int kb = blockIdx.x * 64;
  const int t = threadIdx.x;
#pragma unroll
  for (int j = 0; j < 8; ++j) {
    int fi = j * 256 + t;          // float4 index within 64x128 tile
    int k = fi >> 5;               // 32 float4 per row
    int d = (fi & 31) * 4;
    float4 v = ((const float4*)V)[(size_t)(kb + k) * (DH / 4) + (fi & 31)];
    T[k][d + 0] = f2bf(v.x); T[k][d + 1] = f2bf(v.y);
    T[k][d + 2] = f2bf(v.z); T[k][d + 3] = f2bf(v.w);
  }
  __syncthreads();
  const int d = t >> 1;
  const int kh = (t & 1) * 32;
#pragma unroll
  for (int i = 0; i < 8; ++i) {
    s16x4 o;
    o.x = T[kh + 4 * i + 0][d]; o.y = T[kh + 4 * i + 1][d];
    o.z = T[kh + 4 * i + 2][d]; o.w = T[kh + 4 * i + 3][d];
    *(s16x4*)(Vt + (size_t)d * SK + kb + kh + 4 * i) = o;
  }
}

// ---- main: flash attention, 32 q-rows/block, 4 waves = 2 strips x 2 K-halves ----
__global__ __launch_bounds__(256) void attn_kernel(const float* __restrict__ Q,
                                                   const short* __restrict__ Khi,
                                                   const short* __restrict__ Klo,
                                                   const short* __restrict__ Vt,
                                                   float* __restrict__ out) {
  __shared__ short Kshh[2][BK][136];  // [half][key][d] hi  34816 B
  __shared__ short Kshl[2][BK][136];  // [half][key][d] lo  34816 B
  __shared__ short Vsh[2][DH][72];    // [half][d][key]     36864 B
  __shared__ short Psh[4][16][72];    // [wave][q][key]      9216 B
  __shared__ float mO[2][16][DH];     // merge buffer       16384 B
  __shared__ float mM[2][16];
  __shared__ float mL[2][16];

  const int tid = threadIdx.x;
  const int w = tid >> 6;
  const int lane = tid & 63;
  const int strip = w & 1;            // which 16-row q strip
  const int half = w >> 1;            // which K half
  const int quad = lane >> 4;
  const int l16 = lane & 15;
  const int ht = tid & 127;           // thread id within the half-block
  const int qrow0 = blockIdx.x * 32 + strip * 16;

  // Q A-fragments hi+lo: lane holds Q[qrow0 + l16][kc*32 + quad*8 + j]
  bf16x8 qf[4], ql[4];
  {
    const float* qp = Q + (size_t)(qrow0 + l16) * DH + quad * 8;
#pragma unroll
    for (int kc = 0; kc < 4; ++kc) {
      float4 a = *(const float4*)(qp + kc * 32);
      float4 b = *(const float4*)(qp + kc * 32 + 4);
      bf16x8 h, l;
      h[0] = f2bf(a.x); l[0] = f2bf(a.x - bf2f(h[0]));
      h[1] = f2bf(a.y); l[1] = f2bf(a.y - bf2f(h[1]));
      h[2] = f2bf(a.z); l[2] = f2bf(a.z - bf2f(h[2]));
      h[3] = f2bf(a.w); l[3] = f2bf(a.w - bf2f(h[3]));
      h[4] = f2bf(b.x); l[4] = f2bf(b.x - bf2f(h[4]));
      h[5] = f2bf(b.y); l[5] = f2bf(b.y - bf2f(h[5]));
      h[6] = f2bf(b.z); l[6] = f2bf(b.z - bf2f(h[6]));
      h[7] = f2bf(b.w); l[7] = f2bf(b.w - bf2f(h[7]));
      qf[kc] = h; ql[kc] = l;
    }
  }

  f32x4 of[8];
#pragma unroll
  for (int nt = 0; nt < 8; ++nt) of[nt] = (f32x4){0.f, 0.f, 0.f, 0.f};
  float m_r[4] = {-INFINITY, -INFINITY, -INFINITY, -INFINITY};
  float l_r[4] = {0.f, 0.f, 0.f, 0.f};

  for (int it = 0; it < (SK / 2) / BK; ++it) {
    const int kb = half * (SK / 2) + it * BK;
    // stage K hi/lo tiles + V tile (bf16, coalesced 16B chunks)
    {
      const short* srch = Khi + (size_t)kb * DH;
      const short* srcl = Klo + (size_t)kb * DH;
#pragma unroll
      for (int j = 0; j < 8; ++j) {
        int c = j * 128 + ht;
        *(bf16x8*)(&Kshh[half][c >> 4][(c & 15) * 8]) = *(const bf16x8*)(srch + c * 8);
      }
#pragma unroll
      for (int j = 0; j < 8; ++j) {
        int c = j * 128 + ht;
        *(bf16x8*)(&Kshl[half][c >> 4][(c & 15) * 8]) = *(const bf16x8*)(srcl + c * 8);
      }
#pragma unroll
      for (int j = 0; j < 8; ++j) {
        int d = j * 16 + (ht >> 3);
        int cc = (ht & 7) * 8;
        *(bf16x8*)(&Vsh[half][d][cc]) = *(const bf16x8*)(Vt + (size_t)d * SK + kb + cc);
      }
    }
    __syncthreads();

    // S = Q . K^T  (16 x 64 per wave), split-precision: qh*kh + qh*kl + ql*kh
    f32x4 acc[4];
#pragma unroll
    for (int kt = 0; kt < 4; ++kt) {
      f32x4 a = (f32x4){0.f, 0.f, 0.f, 0.f};
      const short* krh = &Kshh[half][kt * 16 + l16][quad * 8];
      const short* krl = &Kshl[half][kt * 16 + l16][quad * 8];
#pragma unroll
      for (int kc = 0; kc < 4; ++kc) {
        bf16x8 bh = *(const bf16x8*)(krh + kc * 32);
        bf16x8 bl = *(const bf16x8*)(krl + kc * 32);
        a = __builtin_amdgcn_mfma_f32_16x16x32_bf16(qf[kc], bh, a, 0, 0, 0);
        a = __builtin_amdgcn_mfma_f32_16x16x32_bf16(qf[kc], bl, a, 0, 0, 0);
        a = __builtin_amdgcn_mfma_f32_16x16x32_bf16(ql[kc], bh, a, 0, 0, 0);
      }
      acc[kt] = a;
    }

    // online softmax, rows = quad*4 + r
#pragma unroll
    for (int r = 0; r < 4; ++r) {
      float mx = fmaxf(fmaxf(acc[0][r], acc[1][r]), fmaxf(acc[2][r], acc[3][r]));
      mx = fmaxf(mx, __shfl_xor(mx, 1));
      mx = fmaxf(mx, __shfl_xor(mx, 2));
      mx = fmaxf(mx, __shfl_xor(mx, 4));
      mx = fmaxf(mx, __shfl_xor(mx, 8));
      float Mn = fmaxf(m_r[r], mx);
      float alpha = exp2f((m_r[r] - Mn) * L2E);
      m_r[r] = Mn;
      float s = 0.f;
      float p[4];
#pragma unroll
      for (int kt = 0; kt < 4; ++kt) {
        p[kt] = exp2f((acc[kt][r] - Mn) * L2E);
        s += p[kt];
      }
      s += __shfl_xor(s, 1);
      s += __shfl_xor(s, 2);
      s += __shfl_xor(s, 4);
      s += __shfl_xor(s, 8);
      l_r[r] = l_r[r] * alpha + s;
#pragma unroll
      for (int nt = 0; nt < 8; ++nt) of[nt][r] *= alpha;
#pragma unroll
      for (int kt = 0; kt < 4; ++kt)
        Psh[w][quad * 4 + r][kt * 16 + l16] = f2bf(p[kt]);
    }

    // make this wave's P writes visible to its own A-frag reads
    asm volatile("s_waitcnt lgkmcnt(0)" ::: "memory");

    // O += P . V
#pragma unroll
    for (int kc2 = 0; kc2 < 2; ++kc2) {
      bf16x8 pa = *(const bf16x8*)(&Psh[w][l16][kc2 * 32 + quad * 8]);
#pragma unroll
      for (int nt = 0; nt < 8; ++nt) {
        bf16x8 vb = *(const bf16x8*)(&Vsh[half][nt * 16 + l16][kc2 * 32 + quad * 8]);
        of[nt] = __builtin_amdgcn_mfma_f32_16x16x32_bf16(pa, vb, of[nt], 0, 0, 0);
      }
    }
    __syncthreads();
  }

  // merge the two K-halves per strip
  if (half == 1) {
#pragma unroll
    for (int nt = 0; nt < 8; ++nt)
#pragma unroll
      for (int r = 0; r < 4; ++r)
        mO[strip][quad * 4 + r][nt * 16 + l16] = of[nt][r];
    if (l16 == 0) {
#pragma unroll
      for (int r = 0; r < 4; ++r) {
        mM[strip][quad * 4 + r] = m_r[r];
        mL[strip][quad * 4 + r] = l_r[r];
      }
    }
  }
  __syncthreads();
  if (half == 0) {
#pragma unroll
    for (int r = 0; r < 4; ++r) {
      float m2 = mM[strip][quad * 4 + r];
      float l2 = mL[strip][quad * 4 + r];
      float Mn = fmaxf(m_r[r], m2);
      float a1 = exp2f((m_r[r] - Mn) * L2E);
      float a2 = exp2f((m2 - Mn) * L2E);
      float inv = 1.f / (l_r[r] * a1 + l2 * a2);
      float* orow = out + (size_t)(qrow0 + quad * 4 + r) * DH + l16;
#pragma unroll
      for (int nt = 0; nt < 8; ++nt) {
        float o2 = mO[strip][quad * 4 + r][nt * 16 + l16];
        orow[nt * 16] = (of[nt][r] * a1 + o2 * a2) * inv;
      }
    }
  }
}

extern "C" void kernel_launch(void* const* d_in, const int* in_sizes, int n_in,
                              void* d_out, int out_size, void* d_ws, size_t ws_size,
                              hipStream_t stream) {
  const float* Q = (const float*)d_in[0];
  const float* K = (const float*)d_in[1];
  const float* V = (const float*)d_in[2];
  float* out = (float*)d_out;
  short* Khi = (short*)d_ws;                            // 2 MB bf16 K hi
  short* Klo = (short*)d_ws + (size_t)SK * DH;          // 2 MB bf16 K lo
  short* Vt  = (short*)d_ws + (size_t)2 * SK * DH;      // 2 MB bf16 V^T
  cvt_k_kernel<<<(SK * DH / 4) / 256, 256, 0, stream>>>(K, Khi, Klo);
  tr_v_kernel<<<SK / 64, 256, 0, stream>>>(V, Vt);
  attn_kernel<<<SQ / 32, 256, 0, stream>>>(Q, Khi, Klo, Vt, out);
}